// Round 3
// baseline (443.155 us; speedup 1.0000x reference)
//
#include <hip/hip_runtime.h>

// NMS 3x3, replicate pad, strict >, running max initialized at 0.
// x: (8, 32, 512, 512) fp32. out = x * (x > max(0, 8 neighbors)).
//
// Register-rolling separable stencil, no LDS, NO scalar halo loads.
// Each wave64 owns a full 512-col row: lane L holds float4 groups at cols
// 4L (half A) and 256+4L (half B). Horizontal halos come from wave
// shuffles (shfl_up/down for lane neighbors, shfl broadcasts to stitch the
// A|B seam at col 255/256); image edges clamp in-register (replicate pad).
// Separable trick: per row compute h2 = max(left,right), h3 = max(h2,v);
// output row r needs only m8 = max(h3[r-1], h2[r], h3[r+1]).
// Each wave rolls RPT=32 rows -> vertical halo 34/32 = 1.0625x reads.
// Per wave-row VMEM: exactly 2 coalesced dwordx4 loads + 2 dwordx4 stores.

#define IMG_W 512
#define IMG_H 512
#define RPT 32
#define WAVES 4
#define THREADS (WAVES * 64)
#define BLOCK_ROWS (WAVES * RPT)   // 128 rows per block

__device__ __forceinline__ float4 vmax4(float4 a, float4 b) {
    return make_float4(fmaxf(a.x, b.x), fmaxf(a.y, b.y),
                       fmaxf(a.z, b.z), fmaxf(a.w, b.w));
}

struct RowState { float4 h3A, h2A, vA, h3B, h2B, vB; };

__global__ __launch_bounds__(THREADS)
void nms3x3_kernel(const float* __restrict__ x, float* __restrict__ out) {
    const int lane = threadIdx.x & 63;
    const int wave = threadIdx.x >> 6;
    const int r0   = blockIdx.x * BLOCK_ROWS + wave * RPT;
    const size_t plane = (size_t)blockIdx.y * IMG_H * IMG_W;
    const float* img  = x + plane;
    float*       oimg = out + plane;
    const int cA = lane << 2;          // cols 4L .. 4L+3
    const int cB = 256 + (lane << 2);  // cols 256+4L .. 256+4L+3

    auto loadrow = [&](int r, RowState& o) {
        r = min(IMG_H - 1, max(0, r));
        const float* rowp = img + (size_t)r * IMG_W;
        const float4 vA = *(const float4*)(rowp + cA);
        const float4 vB = *(const float4*)(rowp + cB);
        // halo scalars via wave shuffles (uniform control flow, all lanes)
        const float aw_l = __shfl_up(vA.w, 1);    // lane-1's col 4L-1
        const float ax_r = __shfl_down(vA.x, 1);  // lane+1's col 4L+4
        const float bw_l = __shfl_up(vB.w, 1);
        const float bx_r = __shfl_down(vB.x, 1);
        const float aw63 = __shfl(vA.w, 63);      // col 255 (seam)
        const float bx0  = __shfl(vB.x, 0);       // col 256 (seam)
        const float sLA = (lane == 0)  ? vA.x : aw_l;  // col 0: replicate
        const float sRA = (lane == 63) ? bx0  : ax_r;  // col 255's right = 256
        const float sLB = (lane == 0)  ? aw63 : bw_l;  // col 256's left = 255
        const float sRB = (lane == 63) ? vB.w : bx_r;  // col 511: replicate
        const float4 lA = make_float4(sLA, vA.x, vA.y, vA.z);
        const float4 rA = make_float4(vA.y, vA.z, vA.w, sRA);
        o.h2A = vmax4(lA, rA); o.h3A = vmax4(o.h2A, vA); o.vA = vA;
        const float4 lB = make_float4(sLB, vB.x, vB.y, vB.z);
        const float4 rB = make_float4(vB.y, vB.z, vB.w, sRB);
        o.h2B = vmax4(lB, rB); o.h3B = vmax4(o.h2B, vB); o.vB = vB;
    };

    RowState p, c, n;
    loadrow(r0 - 1, p);
    loadrow(r0,     c);

#pragma unroll 8
    for (int k = 0; k < RPT; ++k) {
        loadrow(r0 + k + 1, n);
        const float4 mA = vmax4(vmax4(p.h3A, n.h3A), c.h2A);
        const float4 mB = vmax4(vmax4(p.h3B, n.h3B), c.h2B);
        float4 oA, oB;
        oA.x = (c.vA.x > fmaxf(mA.x, 0.0f)) ? c.vA.x : 0.0f;
        oA.y = (c.vA.y > fmaxf(mA.y, 0.0f)) ? c.vA.y : 0.0f;
        oA.z = (c.vA.z > fmaxf(mA.z, 0.0f)) ? c.vA.z : 0.0f;
        oA.w = (c.vA.w > fmaxf(mA.w, 0.0f)) ? c.vA.w : 0.0f;
        oB.x = (c.vB.x > fmaxf(mB.x, 0.0f)) ? c.vB.x : 0.0f;
        oB.y = (c.vB.y > fmaxf(mB.y, 0.0f)) ? c.vB.y : 0.0f;
        oB.z = (c.vB.z > fmaxf(mB.z, 0.0f)) ? c.vB.z : 0.0f;
        oB.w = (c.vB.w > fmaxf(mB.w, 0.0f)) ? c.vB.w : 0.0f;
        float* orow = oimg + (size_t)(r0 + k) * IMG_W;
        *(float4*)(orow + cA) = oA;
        *(float4*)(orow + cB) = oB;
        p = c; c = n;
    }
}

extern "C" void kernel_launch(void* const* d_in, const int* in_sizes, int n_in,
                              void* d_out, int out_size, void* d_ws, size_t ws_size,
                              hipStream_t stream) {
    const float* x = (const float*)d_in[0];
    float* out     = (float*)d_out;
    dim3 grid(IMG_H / BLOCK_ROWS, 8 * 32);   // 4 x 256 = 1024 blocks
    nms3x3_kernel<<<grid, dim3(THREADS), 0, stream>>>(x, out);
}